// Round 8
// baseline (261.423 us; speedup 1.0000x reference)
//
#include <hip/hip_runtime.h>
#include <stdint.h>

typedef __bf16 bf16_t;
typedef __bf16 bf16x8 __attribute__((ext_vector_type(8)));
typedef __bf16 bf16x4 __attribute__((ext_vector_type(4)));
typedef float  f32x4  __attribute__((ext_vector_type(4)));

#define DEV __device__ __forceinline__

constexpr int S = 2048, D = 1024, BATCH = 4, MF = BATCH * S;

// async global->LDS, 16B per lane. LDS dest is wave-uniform base + lane*16.
DEV void gload16(const void* g, void* l) {
  __builtin_amdgcn_global_load_lds(
      (const __attribute__((address_space(1))) void*)g,
      (__attribute__((address_space(3))) void*)(uint32_t)(uintptr_t)l,
      16, 0, 0);
}

// ---------------------------------------------------------------------------
// bf16 NT GEMM body: C[m][n] = sum_k A[m][k]*B[n][k], fp32 acc.
// Tile 128x128, 256 thr (4 waves, 2x2 of 64x64). 16-B chunks XOR-swizzled
// by (row&7) on the GLOBAL source side -> 0 bank conflicts.
// NSUB = 64-col sub-tiles per K-step (BK = 64*NSUB). NSUB=2 doubles
// MFMA-per-barrier for block-count-capped kernels (pv: 2 blocks/CU) at no
// occupancy cost; keep NSUB=1 where 4 blocks/CU are resident (qkv) per m132.
// K-accumulation order is identical for both (strictly increasing k).
// EP: 1 = QKV split: q/k -> fp8 [MF][D], vw transposed bf16 -> vwT[b][D][S]
//     4 = plain bf16 out, ldc = D (WvoT precompute)
//     5 = FINAL: out = acc * invl_lds[local row] + bo[n], fp32 (PV+folded Wo)
// NOTE (R3 lesson): with tm on the fast grid axis, default dispatch already
// gives XCD x the tiles tm===x (mod 8) -> per-XCD A footprint L2-fits.
// Do NOT remap blockIdx.
// ---------------------------------------------------------------------------
template<int EP, int NSUB>
DEV void gemm_body(int tm, int tn, int bz,
                   const bf16_t* __restrict__ A, const bf16_t* __restrict__ B,
                   void* __restrict__ C0, void* __restrict__ C1,
                   void* __restrict__ C2, const float* __restrict__ aux,
                   int K, int kmax, bf16_t* ldsA, bf16_t* ldsB)
{
  const int m0 = tm * 128, n0 = tn * 128;
  const int tid  = threadIdx.x;
  const int lane = tid & 63;
  const int wave = tid >> 6;
  const int wm = wave & 1, wn = wave >> 1;
  const int l8r = lane >> 3;                  // row within 8-row staging block
  const int swz = ((lane & 7) ^ (lane >> 3)) * 8;  // swizzled k-chunk (elems)
  const int cl  = lane & 15;                  // fragment m/n index
  const int qd  = lane >> 4;                  // quad -> k-slice
  const int ch0 = ((qd ^ (cl & 7)) * 8);      // swizzled read chunk, kk=0

  f32x4 acc[4][4] = {};

  for (int k0 = 0; k0 < kmax; k0 += 64 * NSUB) {
    #pragma unroll
    for (int h = 0; h < NSUB; ++h) {
      #pragma unroll
      for (int t = 0; t < 4; ++t) {
        const int rb = wave * 4 + t;
        gload16(A + (long)(m0 + rb * 8 + l8r) * K + (k0 + h * 64 + swz),
                &ldsA[h * 8192 + rb * 512]);
        gload16(B + (long)(n0 + rb * 8 + l8r) * K + (k0 + h * 64 + swz),
                &ldsB[h * 8192 + rb * 512]);
      }
    }
    __syncthreads();
    #pragma unroll
    for (int h = 0; h < NSUB; ++h) {
      #pragma unroll
      for (int kk = 0; kk < 64; kk += 32) {
        bf16x8 af[4], bg[4];
        #pragma unroll
        for (int i = 0; i < 4; ++i)
          af[i] = *(const bf16x8*)&ldsA[h * 8192 + (wm * 64 + i * 16 + cl) * 64 + (ch0 ^ kk)];
        #pragma unroll
        for (int j = 0; j < 4; ++j)
          bg[j] = *(const bf16x8*)&ldsB[h * 8192 + (wn * 64 + j * 16 + cl) * 64 + (ch0 ^ kk)];
        #pragma unroll
        for (int i = 0; i < 4; ++i)
          #pragma unroll
          for (int j = 0; j < 4; ++j)
            acc[i][j] = __builtin_amdgcn_mfma_f32_16x16x32_bf16(af[i], bg[j], acc[i][j], 0, 0, 0);
      }
    }
    __syncthreads();
  }

  // Epilogues. C/D layout: col = lane&15, row = (lane>>4)*4 + reg.
  #pragma unroll
  for (int i = 0; i < 4; ++i) {
    const int gm0 = m0 + wm * 64 + i * 16 + qd * 4;

    if (EP == 1) {                            // QK (fp8) + VW (bf16) split
      uint8_t* q8 = (uint8_t*)C0;
      uint8_t* k8 = (uint8_t*)C1;
      bf16_t* vwT = (bf16_t*)C2;
      #pragma unroll
      for (int j = 0; j < 4; ++j) {
        const int gn  = n0 + wn * 64 + j * 16 + cl;
        const int sec = gn >> 10, ln = gn & 1023;
        const float bn = aux[gn];
        if (sec == 2) {                       // vw: store transposed, 4x bf16
          const int z = gm0 >> 11, s0 = gm0 & 2047;
          bf16x4 v4;
          #pragma unroll
          for (int r = 0; r < 4; ++r) v4[r] = (bf16_t)(acc[i][j][r] + bn);
          *(bf16x4*)&vwT[((long)z * D + ln) * S + s0] = v4;
        } else {
          uint8_t* dst = (sec == 0) ? q8 : k8;
          #pragma unroll
          for (int r = 0; r < 4; ++r) {
            const float v = acc[i][j][r] + bn;
            const int p = __builtin_amdgcn_cvt_pk_fp8_f32(v, v, 0, false);
            dst[(long)(gm0 + r) * D + ln] = (uint8_t)(p & 0xFF);
          }
        }
      }
    }

    if (EP == 5) {                            // FINAL: fp32 out, LDS invl + bo
      float* out = (float*)C0 + (long)bz * S * D;
      const float* bo = (const float*)C1;
      const float* invl_l = aux;              // LDS, indexed by tile-local row
      float scl[4];
      #pragma unroll
      for (int r = 0; r < 4; ++r) scl[r] = invl_l[wm * 64 + i * 16 + qd * 4 + r];
      #pragma unroll
      for (int j = 0; j < 4; ++j) {
        const int gn = n0 + wn * 64 + j * 16 + cl;
        const float bn = bo[gn];
        #pragma unroll
        for (int r = 0; r < 4; ++r)
          out[(long)(gm0 + r) * D + gn] = acc[i][j][r] * scl[r] + bn;
      }
    }

    if (EP == 4) {                            // plain bf16 out (Wvo precomp)
      bf16_t* Co = (bf16_t*)C0;
      #pragma unroll
      for (int j = 0; j < 4; ++j) {
        const int gn = n0 + wn * 64 + j * 16 + cl;
        #pragma unroll
        for (int r = 0; r < 4; ++r)
          Co[(long)(gm0 + r) * D + gn] = (bf16_t)acc[i][j][r];
      }
    }
  }
}

// QK+VW projection: plain grid (64, 24), NSUB=1 (4 blocks/CU resident; BK=128
// would cut to 2 -> m132 regression regime).
__global__ __launch_bounds__(256, 4) void gemm_qkv(
    const bf16_t* __restrict__ A, const bf16_t* __restrict__ B,
    uint8_t* q8, uint8_t* k8, bf16_t* vwT, const float* __restrict__ bias)
{
  __shared__ __align__(16) bf16_t lA[128 * 64], lB[128 * 64];
  gemm_body<1, 1>(blockIdx.x, blockIdx.y, 0, A, B, q8, k8, vwT, bias,
                  1024, 1024, lA, lB);
}

// ---------------------------------------------------------------------------
// fp8 scores kernel (128x128 geometry, BK=256 = 4 sub-tiles):
// probs = exp(q8·k8^T / 32) causal, bf16 + partial sums.
// LDS rows = 64 fp8 = 64 B per sub-tile; 16-B granules XOR-swizzled by
// (row>>1)&3 (global-source side) -> <=2-way conflicts (free).
// 544 blocks (2.1/CU, block-count-capped) -> BK=256 gives 128 MFMA/wave per
// barrier at no occupancy cost (64 KB LDS, residency cap 2/CU = block supply).
// R7 product model: MFMA/barrier x blocks/CU is the lever in this regime.
// ---------------------------------------------------------------------------
__global__ __launch_bounds__(256, 2) void gemm_sc8(
    const uint8_t* __restrict__ q8g, const uint8_t* __restrict__ k8g,
    bf16_t* __restrict__ probs_g, float* __restrict__ part)
{
  __shared__ __align__(16) uint8_t lA[4][128 * 64], lB[4][128 * 64];
  const int l = blockIdx.x, xcd = l & 7, idx = l >> 3;
  const int bz = xcd >> 1;
  const int t  = (xcd & 1) * 68 + idx;             // triangular index 0..135
  int tm = (int)((sqrtf(8.0f * t + 1.0f) - 1.0f) * 0.5f);
  while ((tm + 1) * (tm + 2) / 2 <= t) ++tm;
  while (tm * (tm + 1) / 2 > t) --tm;
  const int tn = t - tm * (tm + 1) / 2;
  const int m0 = tm * 128, n0 = tn * 128;
  const uint8_t* q8 = q8g + (long)bz * S * D;
  const uint8_t* k8 = k8g + (long)bz * S * D;

  const int tid  = threadIdx.x;
  const int lane = tid & 63;
  const int wave = tid >> 6;
  const int wm = wave & 1, wn = wave >> 1;
  const int srow = lane >> 2;                      // staging row in 16-slab
  const int sgr  = (lane & 3) ^ ((lane >> 3) & 3); // swizzled source granule
  const int cl = lane & 15, qd = lane >> 4;
  const int sfr = (cl >> 1) & 3;                   // frag-read swizzle key
  const int half8 = (qd & 1) * 8;

  f32x4 acc[4][4] = {};

  for (int k0 = 0; k0 < 1024; k0 += 256) {
    #pragma unroll
    for (int h = 0; h < 4; ++h) {
      #pragma unroll
      for (int tt = 0; tt < 2; ++tt) {
        const int rb = wave * 2 + tt;              // 16-row slab (0..7)
        const int gr = rb * 16 + srow;
        gload16(q8 + (long)(m0 + gr) * 1024 + k0 + h * 64 + sgr * 16,
                &lA[h][rb * 1024]);
        gload16(k8 + (long)(n0 + gr) * 1024 + k0 + h * 64 + sgr * 16,
                &lB[h][rb * 1024]);
      }
    }
    __syncthreads();
    #pragma unroll
    for (int h = 0; h < 4; ++h) {
      #pragma unroll
      for (int kk = 0; kk < 2; ++kk) {
        long a[4], b[4];
        const int pg = ((kk << 1) + (qd >> 1)) ^ sfr;
        #pragma unroll
        for (int i = 0; i < 4; ++i)
          a[i] = *(const long*)&lA[h][(wm * 64 + i * 16 + cl) * 64 + pg * 16 + half8];
        #pragma unroll
        for (int j = 0; j < 4; ++j)
          b[j] = *(const long*)&lB[h][(wn * 64 + j * 16 + cl) * 64 + pg * 16 + half8];
        #pragma unroll
        for (int i = 0; i < 4; ++i)
          #pragma unroll
          for (int j = 0; j < 4; ++j)
            acc[i][j] = __builtin_amdgcn_mfma_f32_16x16x32_fp8_fp8(a[i], b[j], acc[i][j], 0, 0, 0);
      }
    }
    __syncthreads();
  }

  // epilogue: exp(acc/32) causal -> bf16 probs + partial row sums
  bf16_t* probs = probs_g + (long)bz * S * S;
  #pragma unroll
  for (int i = 0; i < 4; ++i) {
    const int gm0 = m0 + wm * 64 + i * 16 + qd * 4;
    float ls[4] = {0.f, 0.f, 0.f, 0.f};
    #pragma unroll
    for (int j = 0; j < 4; ++j) {
      const int gn = n0 + wn * 64 + j * 16 + cl;
      #pragma unroll
      for (int r = 0; r < 4; ++r) {
        const int gm = gm0 + r;
        const float e = (gn <= gm) ? __expf(acc[i][j][r] * 0.03125f) : 0.0f;
        probs[(long)gm * S + gn] = (bf16_t)e;
        ls[r] += e;
      }
    }
    #pragma unroll
    for (int r = 0; r < 4; ++r) {
      float v = ls[r];
      v += __shfl_xor(v, 1); v += __shfl_xor(v, 2);
      v += __shfl_xor(v, 4); v += __shfl_xor(v, 8);
      if (cl == 0)
        part[((long)bz * S + (gm0 + r)) * 32 + tn * 2 + wn] = v;
    }
  }
}

// Final PV(+folded Wo): 512 blocks (2/CU, block-count-capped) -> NSUB=2
// (BK=128, 64 KB LDS) doubles MFMA-per-barrier at no occupancy cost.
// (BK=256 would need 128 KB -> 1 block/CU, m132 regression regime.)
// Per-CU exact K balance: idx<32 take long-K m's {15,13,11,9}-half, idx>=32
// take {0,2,4,6}+half -> every CU gets exactly 17 k-tiles.
// Computes inv row sums in the prologue (folds reduce_invl kernel).
__global__ __launch_bounds__(256, 2) void gemm_pv_out(
    const bf16_t* __restrict__ probs, const bf16_t* __restrict__ vwT,
    float* out, const float* __restrict__ part, const float* __restrict__ bo)
{
  __shared__ __align__(16) bf16_t lA[2 * 128 * 64], lB[2 * 128 * 64];
  __shared__ float invl_s[128];
  const int l = blockIdx.x, xcd = l & 7, idx = l >> 3;
  const int bz = xcd >> 1, half = xcd & 1;
  const int g = (idx >> 3) & 3, tn = idx & 7;
  const int tm = (idx < 32) ? (15 - half - 2 * g) : (2 * g + half);
  const int kmax = (tm + 1) * 128;

  if (threadIdx.x < 128) {                   // invl for this tile's 128 rows
    const int row = tm * 128 + threadIdx.x;
    const int cnt = (tm + 1) * 2;            // valid partials (stride-32 slab)
    const float* p = part + ((long)bz * S + row) * 32;
    float s = 0.f;
    for (int j = 0; j < cnt; ++j) s += p[j];
    invl_s[threadIdx.x] = 1.0f / s;
  }
  __syncthreads();

  gemm_body<5, 2>(tm, tn, bz, probs + (long)bz * S * S, vwT + (long)bz * D * S,
                  out, (void*)bo, nullptr, invl_s, 2048, kmax, lA, lB);
}

// WvoT[c][i] = sum_n Wv[i][n] * Wo[n][c]  (so vw = x @ (Wv@Wo)).
__global__ __launch_bounds__(256, 4) void gemm_wvo(
    const bf16_t* __restrict__ WoT, const bf16_t* __restrict__ WvN,
    bf16_t* WvoT)
{
  __shared__ __align__(16) bf16_t lA[128 * 64], lB[128 * 64];
  gemm_body<4, 1>(blockIdx.x, blockIdx.y, 0, WoT, WvN, WvoT, nullptr, nullptr,
                  nullptr, 1024, 1024, lA, lB);
}

// ---------------------------------------------------------------------------
// Fused preamble (R8): one launch replaces cvt_x + cvt_w_t4 + bias_build.
// All three parts are independent: bias now reads fp32 Wo directly, rounding
// each element through bf16 so the result is numerically identical to the
// old WoT-based path (no dependency on the cvt_w part).
// blocks [0, 8192):        x fp32 -> bf16, 4 elems/thread
// blocks [8192, 12288):    weights -> bf16 (z = idx>>10: Wq^T, Wk^T, Wv, Wo^T)
// blocks [12288, 12548):   bias build (bvo via Wo, bq/bk copy)
// ---------------------------------------------------------------------------
__global__ __launch_bounds__(256) void preamble(
    const float* __restrict__ x, bf16x4* __restrict__ x_b,
    const float* __restrict__ Wq, const float* __restrict__ Wk,
    const float* __restrict__ Wv, const float* __restrict__ Wo,
    bf16_t* __restrict__ Wall,
    const float* __restrict__ bq, const float* __restrict__ bk,
    const float* __restrict__ bv, float* __restrict__ o)
{
  __shared__ float t[32][33];
  const int b = blockIdx.x;
  const int tid = threadIdx.x;

  if (b < 8192) {                             // ---- cvt_x ----
    const int i = b * 256 + tid;              // exact: 8192*256 = MF*D/4
    float4 f = ((const float4*)x)[i];
    bf16x4 v;
    v.x = (__bf16)f.x; v.y = (__bf16)f.y; v.z = (__bf16)f.z; v.w = (__bf16)f.w;
    x_b[i] = v;
    return;
  }

  if (b < 12288) {                            // ---- cvt_w ----
    const int idx = b - 8192;
    const int bx = idx & 31, by = (idx >> 5) & 31, z = idx >> 10;
    const int zmap[4] = {0, 1, 3, 4};
    const float* W = (z == 0) ? Wq : (z == 1) ? Wk : (z == 2) ? Wv : Wo;
    bf16_t* WT = Wall + (size_t)zmap[z] * D * D;
    const int tx = tid & 31, ty = tid >> 5;   // 32 x 8

    if (z == 2) {                             // Wv: plain cast, no transpose
      #pragma unroll
      for (int dy = 0; dy < 32; dy += 8) {
        const long i2 = (long)(by * 32 + ty + dy) * 1024 + bx * 32 + tx;
        WT[i2] = (bf16_t)W[i2];
      }
      return;
    }
    #pragma unroll
    for (int dy = 0; dy < 32; dy += 8)
      t[ty + dy][tx] = W[(long)(by * 32 + ty + dy) * 1024 + bx * 32 + tx];
    __syncthreads();
    #pragma unroll
    for (int dy = 0; dy < 32; dy += 8)
      WT[(long)(bx * 32 + ty + dy) * 1024 + by * 32 + tx] = (bf16_t)t[tx][ty + dy];
    return;
  }

  // ---- bias ----
  const int bb = b - 12288;
  if (bb >= 256) {
    const int i = (bb - 256) * 256 + tid;     // 0..1023
    o[i] = bq[i];
    o[1024 + i] = bk[i];
    return;
  }
  const int wave = tid >> 6, lane = tid & 63;
  const int c = bb * 4 + wave;
  float s = 0.f;
  #pragma unroll
  for (int j = 0; j < 16; ++j) {
    const int e = lane * 16 + j;
    s += bv[e] * (float)(bf16_t)Wo[(long)e * 1024 + c];  // == old bv*WoT path
  }
  #pragma unroll
  for (int sh = 32; sh > 0; sh >>= 1) s += __shfl_xor(s, sh, 64);
  if (lane == 0) o[2048 + c] = s;
}

// ---------------------------------------------------------------------------
extern "C" void kernel_launch(void* const* d_in, const int* in_sizes, int n_in,
                              void* d_out, int out_size, void* d_ws, size_t ws_size,
                              hipStream_t stream) {
  const float* x  = (const float*)d_in[0];
  const float* Wq = (const float*)d_in[1];
  const float* bq = (const float*)d_in[2];
  const float* Wk = (const float*)d_in[3];
  const float* bk = (const float*)d_in[4];
  const float* Wv = (const float*)d_in[5];
  const float* bv = (const float*)d_in[6];
  const float* Wo = (const float*)d_in[7];
  const float* bo = (const float*)d_in[8];
  float* out = (float*)d_out;

  size_t off = 0;
  auto alloc = [&](size_t bytes) -> void* {
    void* p = (char*)d_ws + off;
    off += (bytes + 255) & ~(size_t)255;
    return p;
  };
  bf16_t* x_b   = (bf16_t*)alloc((size_t)MF * D * 2);          // 16.8 MB
  bf16_t* Wall  = (bf16_t*)alloc((size_t)5 * D * D * 2);       // [WqT|WkT|WvoT|WvN|WoT]
  float*  bqkv  = (float*) alloc((size_t)3 * D * 4);
  uint8_t* q8   = (uint8_t*)alloc((size_t)MF * D);             // 8.4 MB fp8
  uint8_t* k8   = (uint8_t*)alloc((size_t)MF * D);             // 8.4 MB fp8
  bf16_t* vwT_b = (bf16_t*)alloc((size_t)BATCH * D * S * 2);   // [b][D][S]
  bf16_t* probs = (bf16_t*)alloc((size_t)BATCH * S * S * 2);   // 33.5 MB
  float*  part  = (float*) alloc((size_t)MF * 32 * 4);         // 1 MB
  bf16_t* WqkvT = Wall;                       // stacked B for QKV: [3D][D]
  bf16_t* WvoT  = Wall + (size_t)2 * D * D;
  bf16_t* WvN   = Wall + (size_t)3 * D * D;   // Wv natural layout, bf16
  bf16_t* WoT   = Wall + (size_t)4 * D * D;

  // 1. fused preamble: x -> bf16; weights -> bf16; bias (all independent)
  preamble<<<dim3(12548), 256, 0, stream>>>(
      x, (bf16x4*)x_b, Wq, Wk, Wv, Wo, Wall, bq, bk, bv, bqkv);

  // 2. WvoT = (Wv@Wo)^T folded weight (so PV emits the final output directly)
  gemm_wvo<<<dim3(8, 8), 256, 0, stream>>>(WoT, WvN, WvoT);

  // 3. fused projection: q/k in fp8 e4m3, vw bf16 transposed
  gemm_qkv<<<dim3(64, 24), 256, 0, stream>>>(x_b, WqkvT, q8, k8, vwT_b, bqkv);

  // 4. scores (fp8 MFMA, 128x128 + BK=256) -> exp(./32) bf16 probs + partials
  gemm_sc8<<<dim3(544), 256, 0, stream>>>(q8, k8, probs, part);

  // 5. out = (P vw) * invl + bo  (final, fp32, BK=128; invl in prologue)
  gemm_pv_out<<<dim3(512), 256, 0, stream>>>(probs, vwT_b, out, part, bo);
}

// Round 9
// 242.542 us; speedup vs baseline: 1.0778x; 1.0778x over previous
//
#include <hip/hip_runtime.h>
#include <stdint.h>

typedef __bf16 bf16_t;
typedef __bf16 bf16x8 __attribute__((ext_vector_type(8)));
typedef __bf16 bf16x4 __attribute__((ext_vector_type(4)));
typedef float  f32x4  __attribute__((ext_vector_type(4)));

#define DEV __device__ __forceinline__

constexpr int S = 2048, D = 1024, BATCH = 4, MF = BATCH * S;

// async global->LDS, 16B per lane. LDS dest is wave-uniform base + lane*16.
DEV void gload16(const void* g, void* l) {
  __builtin_amdgcn_global_load_lds(
      (const __attribute__((address_space(1))) void*)g,
      (__attribute__((address_space(3))) void*)(uint32_t)(uintptr_t)l,
      16, 0, 0);
}

// ---------------------------------------------------------------------------
// bf16 NT GEMM body: C[m][n] = sum_k A[m][k]*B[n][k], fp32 acc.
// Tile 128x128, 256 thr (4 waves, 2x2 of 64x64). 16-B chunks XOR-swizzled
// by (row&7) on the GLOBAL source side -> 0 bank conflicts.
// NSUB = 64-col sub-tiles per K-step (BK = 64*NSUB). NSUB=2 doubles
// MFMA-per-barrier for block-count-capped kernels (pv: 2 blocks/CU) at no
// occupancy cost; keep NSUB=1 where 4 blocks/CU are resident (qkv) per m132.
// R8 lesson: residency cap (LDS) must be >= block supply per CU, else the
// straggler blocks serialize a full extra round.
// EP: 1 = QKV split: q/k -> fp8 [MF][D], vw transposed bf16 -> vwT[b][D][S]
//     4 = plain bf16 out, ldc = D (WvoT precompute)
//     5 = FINAL: out = acc * invl_lds[local row] + bo[n], fp32 (PV+folded Wo)
// NOTE (R3 lesson): with tm on the fast grid axis, default dispatch already
// gives XCD x the tiles tm===x (mod 8) -> per-XCD A footprint L2-fits.
// Do NOT remap blockIdx.
// ---------------------------------------------------------------------------
template<int EP, int NSUB>
DEV void gemm_body(int tm, int tn, int bz,
                   const bf16_t* __restrict__ A, const bf16_t* __restrict__ B,
                   void* __restrict__ C0, void* __restrict__ C1,
                   void* __restrict__ C2, const float* __restrict__ aux,
                   int K, int kmax, bf16_t* ldsA, bf16_t* ldsB)
{
  const int m0 = tm * 128, n0 = tn * 128;
  const int tid  = threadIdx.x;
  const int lane = tid & 63;
  const int wave = tid >> 6;
  const int wm = wave & 1, wn = wave >> 1;
  const int l8r = lane >> 3;                  // row within 8-row staging block
  const int swz = ((lane & 7) ^ (lane >> 3)) * 8;  // swizzled k-chunk (elems)
  const int cl  = lane & 15;                  // fragment m/n index
  const int qd  = lane >> 4;                  // quad -> k-slice
  const int ch0 = ((qd ^ (cl & 7)) * 8);      // swizzled read chunk, kk=0

  f32x4 acc[4][4] = {};

  for (int k0 = 0; k0 < kmax; k0 += 64 * NSUB) {
    #pragma unroll
    for (int h = 0; h < NSUB; ++h) {
      #pragma unroll
      for (int t = 0; t < 4; ++t) {
        const int rb = wave * 4 + t;
        gload16(A + (long)(m0 + rb * 8 + l8r) * K + (k0 + h * 64 + swz),
                &ldsA[h * 8192 + rb * 512]);
        gload16(B + (long)(n0 + rb * 8 + l8r) * K + (k0 + h * 64 + swz),
                &ldsB[h * 8192 + rb * 512]);
      }
    }
    __syncthreads();
    #pragma unroll
    for (int h = 0; h < NSUB; ++h) {
      #pragma unroll
      for (int kk = 0; kk < 64; kk += 32) {
        bf16x8 af[4], bg[4];
        #pragma unroll
        for (int i = 0; i < 4; ++i)
          af[i] = *(const bf16x8*)&ldsA[h * 8192 + (wm * 64 + i * 16 + cl) * 64 + (ch0 ^ kk)];
        #pragma unroll
        for (int j = 0; j < 4; ++j)
          bg[j] = *(const bf16x8*)&ldsB[h * 8192 + (wn * 64 + j * 16 + cl) * 64 + (ch0 ^ kk)];
        #pragma unroll
        for (int i = 0; i < 4; ++i)
          #pragma unroll
          for (int j = 0; j < 4; ++j)
            acc[i][j] = __builtin_amdgcn_mfma_f32_16x16x32_bf16(af[i], bg[j], acc[i][j], 0, 0, 0);
      }
    }
    __syncthreads();
  }

  // Epilogues. C/D layout: col = lane&15, row = (lane>>4)*4 + reg.
  #pragma unroll
  for (int i = 0; i < 4; ++i) {
    const int gm0 = m0 + wm * 64 + i * 16 + qd * 4;

    if (EP == 1) {                            // QK (fp8) + VW (bf16) split
      uint8_t* q8 = (uint8_t*)C0;
      uint8_t* k8 = (uint8_t*)C1;
      bf16_t* vwT = (bf16_t*)C2;
      #pragma unroll
      for (int j = 0; j < 4; ++j) {
        const int gn  = n0 + wn * 64 + j * 16 + cl;
        const int sec = gn >> 10, ln = gn & 1023;
        const float bn = aux[gn];
        if (sec == 2) {                       // vw: store transposed, 4x bf16
          const int z = gm0 >> 11, s0 = gm0 & 2047;
          bf16x4 v4;
          #pragma unroll
          for (int r = 0; r < 4; ++r) v4[r] = (bf16_t)(acc[i][j][r] + bn);
          *(bf16x4*)&vwT[((long)z * D + ln) * S + s0] = v4;
        } else {
          uint8_t* dst = (sec == 0) ? q8 : k8;
          #pragma unroll
          for (int r = 0; r < 4; ++r) {
            const float v = acc[i][j][r] + bn;
            const int p = __builtin_amdgcn_cvt_pk_fp8_f32(v, v, 0, false);
            dst[(long)(gm0 + r) * D + ln] = (uint8_t)(p & 0xFF);
          }
        }
      }
    }

    if (EP == 5) {                            // FINAL: fp32 out, LDS invl + bo
      float* out = (float*)C0 + (long)bz * S * D;
      const float* bo = (const float*)C1;
      const float* invl_l = aux;              // LDS, indexed by tile-local row
      float scl[4];
      #pragma unroll
      for (int r = 0; r < 4; ++r) scl[r] = invl_l[wm * 64 + i * 16 + qd * 4 + r];
      #pragma unroll
      for (int j = 0; j < 4; ++j) {
        const int gn = n0 + wn * 64 + j * 16 + cl;
        const float bn = bo[gn];
        #pragma unroll
        for (int r = 0; r < 4; ++r)
          out[(long)(gm0 + r) * D + gn] = acc[i][j][r] * scl[r] + bn;
      }
    }

    if (EP == 4) {                            // plain bf16 out (Wvo precomp)
      bf16_t* Co = (bf16_t*)C0;
      #pragma unroll
      for (int j = 0; j < 4; ++j) {
        const int gn = n0 + wn * 64 + j * 16 + cl;
        #pragma unroll
        for (int r = 0; r < 4; ++r)
          Co[(long)(gm0 + r) * D + gn] = (bf16_t)acc[i][j][r];
      }
    }
  }
}

// QK+VW projection: plain grid (64, 24), NSUB=1 (4 blocks/CU resident; BK=128
// would cut to 2 -> m132 regression regime).
__global__ __launch_bounds__(256, 4) void gemm_qkv(
    const bf16_t* __restrict__ A, const bf16_t* __restrict__ B,
    uint8_t* q8, uint8_t* k8, bf16_t* vwT, const float* __restrict__ bias)
{
  __shared__ __align__(16) bf16_t lA[128 * 64], lB[128 * 64];
  gemm_body<1, 1>(blockIdx.x, blockIdx.y, 0, A, B, q8, k8, vwT, bias,
                  1024, 1024, lA, lB);
}

// ---------------------------------------------------------------------------
// fp8 scores kernel (128x128 geometry, BK=256 = 4 sub-tiles, 512 blocks):
// probs = exp(q8·k8^T / 32) causal, bf16 + partial sums.
// BK=256 -> 128 MFMA/wave per barrier; 64 KB LDS caps residency at 2/CU, so
// the grid supplies EXACTLY 2/CU (512 blocks): per batch, 128 blocks cover
// the 136 triangle tiles; blocks j<120 take tile t=j+16, blocks j>=120 take
// the two cheap tiles t=j-120 and t=j-112 (pair work <= 10 < max single 16).
// R8 lesson applied: no straggler round. Per-tile math identical -> bit-
// identical output.
// ---------------------------------------------------------------------------
__global__ __launch_bounds__(256, 2) void gemm_sc8(
    const uint8_t* __restrict__ q8g, const uint8_t* __restrict__ k8g,
    bf16_t* __restrict__ probs_g, float* __restrict__ part)
{
  __shared__ __align__(16) uint8_t lA[4][128 * 64], lB[4][128 * 64];
  const int l = blockIdx.x, xcd = l & 7, idx = l >> 3;   // idx 0..63
  const int bz = xcd >> 1;
  const int j = (xcd & 1) * 64 + idx;                    // 0..127 per batch
  const uint8_t* q8 = q8g + (long)bz * S * D;
  const uint8_t* k8 = k8g + (long)bz * S * D;

  const int tid  = threadIdx.x;
  const int lane = tid & 63;
  const int wave = tid >> 6;
  const int wm = wave & 1, wn = wave >> 1;
  const int srow = lane >> 2;                      // staging row in 16-slab
  const int sgr  = (lane & 3) ^ ((lane >> 3) & 3); // swizzled source granule
  const int cl = lane & 15, qd = lane >> 4;
  const int sfr = (cl >> 1) & 3;                   // frag-read swizzle key
  const int half8 = (qd & 1) * 8;

  bf16_t* probs = probs_g + (long)bz * S * S;
  const int ntile = (j < 120) ? 1 : 2;

  for (int p = 0; p < ntile; ++p) {
    const int t = (j < 120) ? (j + 16) : (j - 120 + p * 8);
    int tm = (int)((sqrtf(8.0f * t + 1.0f) - 1.0f) * 0.5f);
    while ((tm + 1) * (tm + 2) / 2 <= t) ++tm;
    while (tm * (tm + 1) / 2 > t) --tm;
    const int tn = t - tm * (tm + 1) / 2;
    const int m0 = tm * 128, n0 = tn * 128;

    f32x4 acc[4][4] = {};

    for (int k0 = 0; k0 < 1024; k0 += 256) {
      #pragma unroll
      for (int h = 0; h < 4; ++h) {
        #pragma unroll
        for (int tt = 0; tt < 2; ++tt) {
          const int rb = wave * 2 + tt;              // 16-row slab (0..7)
          const int gr = rb * 16 + srow;
          gload16(q8 + (long)(m0 + gr) * 1024 + k0 + h * 64 + sgr * 16,
                  &lA[h][rb * 1024]);
          gload16(k8 + (long)(n0 + gr) * 1024 + k0 + h * 64 + sgr * 16,
                  &lB[h][rb * 1024]);
        }
      }
      __syncthreads();
      #pragma unroll
      for (int h = 0; h < 4; ++h) {
        #pragma unroll
        for (int kk = 0; kk < 2; ++kk) {
          long a[4], b[4];
          const int pg = ((kk << 1) + (qd >> 1)) ^ sfr;
          #pragma unroll
          for (int i = 0; i < 4; ++i)
            a[i] = *(const long*)&lA[h][(wm * 64 + i * 16 + cl) * 64 + pg * 16 + half8];
          #pragma unroll
          for (int jj = 0; jj < 4; ++jj)
            b[jj] = *(const long*)&lB[h][(wn * 64 + jj * 16 + cl) * 64 + pg * 16 + half8];
          #pragma unroll
          for (int i = 0; i < 4; ++i)
            #pragma unroll
            for (int jj = 0; jj < 4; ++jj)
              acc[i][jj] = __builtin_amdgcn_mfma_f32_16x16x32_fp8_fp8(a[i], b[jj], acc[i][jj], 0, 0, 0);
        }
      }
      __syncthreads();
    }

    // epilogue: exp(acc/32) causal -> bf16 probs + partial row sums
    #pragma unroll
    for (int i = 0; i < 4; ++i) {
      const int gm0 = m0 + wm * 64 + i * 16 + qd * 4;
      float ls[4] = {0.f, 0.f, 0.f, 0.f};
      #pragma unroll
      for (int jj = 0; jj < 4; ++jj) {
        const int gn = n0 + wn * 64 + jj * 16 + cl;
        #pragma unroll
        for (int r = 0; r < 4; ++r) {
          const int gm = gm0 + r;
          const float e = (gn <= gm) ? __expf(acc[i][jj][r] * 0.03125f) : 0.0f;
          probs[(long)gm * S + gn] = (bf16_t)e;
          ls[r] += e;
        }
      }
      #pragma unroll
      for (int r = 0; r < 4; ++r) {
        float v = ls[r];
        v += __shfl_xor(v, 1); v += __shfl_xor(v, 2);
        v += __shfl_xor(v, 4); v += __shfl_xor(v, 8);
        if (cl == 0)
          part[((long)bz * S + (gm0 + r)) * 32 + tn * 2 + wn] = v;
      }
    }
  }
}

// Final PV(+folded Wo): 512 blocks (2/CU, supply == residency cap) -> NSUB=2
// (BK=128, 64 KB LDS) doubles MFMA-per-barrier at no occupancy cost.
// (BK=256 would need 128 KB -> 1 block/CU, m132 regression regime.)
// Per-CU exact K balance: idx<32 take long-K m's {15,13,11,9}-half, idx>=32
// take {0,2,4,6}+half -> every CU gets exactly 17 k-tiles.
// Computes inv row sums in the prologue (folds reduce_invl kernel).
__global__ __launch_bounds__(256, 2) void gemm_pv_out(
    const bf16_t* __restrict__ probs, const bf16_t* __restrict__ vwT,
    float* out, const float* __restrict__ part, const float* __restrict__ bo)
{
  __shared__ __align__(16) bf16_t lA[2 * 128 * 64], lB[2 * 128 * 64];
  __shared__ float invl_s[128];
  const int l = blockIdx.x, xcd = l & 7, idx = l >> 3;
  const int bz = xcd >> 1, half = xcd & 1;
  const int g = (idx >> 3) & 3, tn = idx & 7;
  const int tm = (idx < 32) ? (15 - half - 2 * g) : (2 * g + half);
  const int kmax = (tm + 1) * 128;

  if (threadIdx.x < 128) {                   // invl for this tile's 128 rows
    const int row = tm * 128 + threadIdx.x;
    const int cnt = (tm + 1) * 2;            // valid partials (stride-32 slab)
    const float* p = part + ((long)bz * S + row) * 32;
    float s = 0.f;
    for (int j = 0; j < cnt; ++j) s += p[j];
    invl_s[threadIdx.x] = 1.0f / s;
  }
  __syncthreads();

  gemm_body<5, 2>(tm, tn, bz, probs + (long)bz * S * S, vwT + (long)bz * D * S,
                  out, (void*)bo, nullptr, invl_s, 2048, kmax, lA, lB);
}

// WvoT[c][i] = sum_n Wv[i][n] * Wo[n][c]  (so vw = x @ (Wv@Wo)).
__global__ __launch_bounds__(256, 4) void gemm_wvo(
    const bf16_t* __restrict__ WoT, const bf16_t* __restrict__ WvN,
    bf16_t* WvoT)
{
  __shared__ __align__(16) bf16_t lA[128 * 64], lB[128 * 64];
  gemm_body<4, 1>(blockIdx.x, blockIdx.y, 0, WoT, WvN, WvoT, nullptr, nullptr,
                  nullptr, 1024, 1024, lA, lB);
}

// fp32 -> bf16 elementwise (x), 4 elems/thread
__global__ __launch_bounds__(256) void cvt_x(
    const float4* __restrict__ in, bf16x4* __restrict__ out, int n4)
{
  const int i = blockIdx.x * 256 + threadIdx.x;
  if (i >= n4) return;
  float4 f = in[i];
  bf16x4 o;
  o.x = (__bf16)f.x; o.y = (__bf16)f.y; o.z = (__bf16)f.z; o.w = (__bf16)f.w;
  out[i] = o;
}

// Weights -> bf16. z=0: Wq^T -> slot0; z=1: Wk^T -> slot1; z=3: Wo^T -> slot4
// (transposed via LDS). z=2: Wv plain cast (natural [i][n]) -> slot3.
// Slot 2 (WvoT) is filled by gemm_wvo.
__global__ __launch_bounds__(256) void cvt_w_t4(
    const float* __restrict__ W0, const float* __restrict__ W1,
    const float* __restrict__ W2, const float* __restrict__ W3,
    bf16_t* __restrict__ dst)
{
  const int zmap[4] = {0, 1, 3, 4};
  const float* W = (blockIdx.z == 0) ? W0 : (blockIdx.z == 1) ? W1
                 : (blockIdx.z == 2) ? W2 : W3;
  bf16_t* WT = dst + (size_t)zmap[blockIdx.z] * D * D;
  const int bx = blockIdx.x, by = blockIdx.y;
  const int tx = threadIdx.x & 31, ty = threadIdx.x >> 5;  // 32 x 8

  if (blockIdx.z == 2) {                      // Wv: plain cast, no transpose
    #pragma unroll
    for (int dy = 0; dy < 32; dy += 8) {
      const long idx = (long)(by * 32 + ty + dy) * 1024 + bx * 32 + tx;
      WT[idx] = (bf16_t)W[idx];
    }
    return;
  }

  __shared__ float t[32][33];
  #pragma unroll
  for (int dy = 0; dy < 32; dy += 8)
    t[ty + dy][tx] = W[(long)(by * 32 + ty + dy) * 1024 + bx * 32 + tx];
  __syncthreads();
  #pragma unroll
  for (int dy = 0; dy < 32; dy += 8)
    WT[(long)(bx * 32 + ty + dy) * 1024 + by * 32 + tx] = (bf16_t)t[tx][ty + dy];
}

// bias build: blocks 0..255 -> bvo[c] = sum_e bv[e]*WoT[c][e], one wave per
// column (coalesced row read + butterfly). Blocks 256..259 copy bq/bk.
__global__ __launch_bounds__(256) void bias_build(
    const float* __restrict__ bq, const float* __restrict__ bk,
    const float* __restrict__ bv, const bf16_t* __restrict__ WoT,
    float* __restrict__ o)
{
  const int b = blockIdx.x;
  if (b >= 256) {
    const int i = (b - 256) * 256 + threadIdx.x;   // 0..1023
    o[i] = bq[i];
    o[1024 + i] = bk[i];
    return;
  }
  const int wave = threadIdx.x >> 6, lane = threadIdx.x & 63;
  const int c = b * 4 + wave;
  const bf16_t* row = WoT + (long)c * 1024 + lane * 16;
  const float*  bvp = bv + lane * 16;
  float s = 0.f;
  #pragma unroll
  for (int j = 0; j < 16; ++j) s += bvp[j] * (float)row[j];
  #pragma unroll
  for (int sh = 32; sh > 0; sh >>= 1) s += __shfl_xor(s, sh, 64);
  if (lane == 0) o[2048 + c] = s;
}

// ---------------------------------------------------------------------------
extern "C" void kernel_launch(void* const* d_in, const int* in_sizes, int n_in,
                              void* d_out, int out_size, void* d_ws, size_t ws_size,
                              hipStream_t stream) {
  const float* x  = (const float*)d_in[0];
  const float* Wq = (const float*)d_in[1];
  const float* bq = (const float*)d_in[2];
  const float* Wk = (const float*)d_in[3];
  const float* bk = (const float*)d_in[4];
  const float* Wv = (const float*)d_in[5];
  const float* bv = (const float*)d_in[6];
  const float* Wo = (const float*)d_in[7];
  const float* bo = (const float*)d_in[8];
  float* out = (float*)d_out;

  size_t off = 0;
  auto alloc = [&](size_t bytes) -> void* {
    void* p = (char*)d_ws + off;
    off += (bytes + 255) & ~(size_t)255;
    return p;
  };
  bf16_t* x_b   = (bf16_t*)alloc((size_t)MF * D * 2);          // 16.8 MB
  bf16_t* Wall  = (bf16_t*)alloc((size_t)5 * D * D * 2);       // [WqT|WkT|WvoT|WvN|WoT]
  float*  bqkv  = (float*) alloc((size_t)3 * D * 4);
  uint8_t* q8   = (uint8_t*)alloc((size_t)MF * D);             // 8.4 MB fp8
  uint8_t* k8   = (uint8_t*)alloc((size_t)MF * D);             // 8.4 MB fp8
  bf16_t* vwT_b = (bf16_t*)alloc((size_t)BATCH * D * S * 2);   // [b][D][S]
  bf16_t* probs = (bf16_t*)alloc((size_t)BATCH * S * S * 2);   // 33.5 MB
  float*  part  = (float*) alloc((size_t)MF * 32 * 4);         // 1 MB
  bf16_t* WqkvT = Wall;                       // stacked B for QKV: [3D][D]
  bf16_t* WvoT  = Wall + (size_t)2 * D * D;
  bf16_t* WvN   = Wall + (size_t)3 * D * D;   // Wv natural layout, bf16
  bf16_t* WoT   = Wall + (size_t)4 * D * D;

  // 1. preamble: x -> bf16; weights -> bf16; bias (bvo via WoT, parallel)
  cvt_x<<<dim3((MF * D / 4 + 255) / 256), 256, 0, stream>>>(
      (const float4*)x, (bf16x4*)x_b, MF * D / 4);
  cvt_w_t4<<<dim3(32, 32, 4), 256, 0, stream>>>(Wq, Wk, Wv, Wo, Wall);
  bias_build<<<dim3(260), 256, 0, stream>>>(bq, bk, bv, WoT, bqkv);

  // 2. WvoT = (Wv@Wo)^T folded weight (so PV emits the final output directly)
  gemm_wvo<<<dim3(8, 8), 256, 0, stream>>>(WoT, WvN, WvoT);

  // 3. fused projection: q/k in fp8 e4m3, vw bf16 transposed
  gemm_qkv<<<dim3(64, 24), 256, 0, stream>>>(x_b, WqkvT, q8, k8, vwT_b, bqkv);

  // 4. scores (fp8 MFMA, 128x128, BK=256, 512 blocks paired) -> probs+partials
  gemm_sc8<<<dim3(512), 256, 0, stream>>>(q8, k8, probs, part);

  // 5. out = (P vw) * invl + bo  (final, fp32, BK=128; invl in prologue)
  gemm_pv_out<<<dim3(512), 256, 0, stream>>>(probs, vwT_b, out, part, bo);
}